// Round 15
// baseline (314.469 us; speedup 1.0000x reference)
//
#include <hip/hip_runtime.h>
#include <hip/hip_bf16.h>

typedef unsigned short u16;
typedef unsigned int u32;
typedef float f32x4 __attribute__((ext_vector_type(4)));
typedef u16 u16x4 __attribute__((ext_vector_type(4)));
typedef u16 u16x8 __attribute__((ext_vector_type(8)));
typedef __bf16 bf16x8 __attribute__((ext_vector_type(8)));

#define OUT_DIM 4096
#define IN_DIM  4096
#define M_DIM   8192   // 4 * 2048

__device__ __forceinline__ u16 f2bf(float f) {
  u32 u = __builtin_bit_cast(u32, f);
  return (u16)((u + 0x7FFFu + ((u >> 16) & 1u)) >> 16);
}

// ---------------------------------------------------------------------------
// Combined prep kernel (single dispatch):
//  blocks [0, 4096): build W row o; blocks [4096, 6144): X f32->bf16.
// ---------------------------------------------------------------------------
__global__ __launch_bounds__(256) void prep_kernel(
    const float* __restrict__ codebook, const float* __restrict__ scales,
    const int* __restrict__ indices, const int* __restrict__ signs,
    const float* __restrict__ X,
    u16* __restrict__ W, u16* __restrict__ Xb) {
  __shared__ float c[IN_DIM];
  const int tid = threadIdx.x;

  if (blockIdx.x < OUT_DIM) {
    const int o = blockIdx.x;
    for (int g = tid; g < IN_DIM / 8; g += 256) {
      const int idx = indices[o * (IN_DIM / 8) + g];
      const int sp  = signs[o * (IN_DIM / 8) + g];
      f32x4 c0 = *(const f32x4*)&codebook[idx * 8];
      f32x4 c1 = *(const f32x4*)&codebook[idx * 8 + 4];
      float v[8] = {c0[0], c0[1], c0[2], c0[3], c1[0], c1[1], c1[2], c1[3]};
#pragma unroll
      for (int j = 0; j < 8; ++j)
        c[g * 8 + j] = ((sp >> j) & 1) ? v[j] : -v[j];
    }
    __syncthreads();
    const float scale = scales[o];
    const float S = 0.70710678118654752440f;
    for (int t = tid; t < IN_DIM / 4; t += 256) {
      float a   = c[t];
      float d1  = c[IN_DIM / 4 + t];
      float d2a = c[IN_DIM / 2 + 2 * t];
      float d2b = c[IN_DIM / 2 + 2 * t + 1];
      float e  = (a + d1) * S;
      float od = (a - d1) * S;
      u16x4 w;
      w[0] = f2bf((e  + d2a) * S * scale);
      w[1] = f2bf((e  - d2a) * S * scale);
      w[2] = f2bf((od + d2b) * S * scale);
      w[3] = f2bf((od - d2b) * S * scale);
      *(u16x4*)&W[(size_t)o * IN_DIM + 4 * t] = w;
    }
  } else {
    const int stride = 2048 * 256;
    const int n8 = (M_DIM * IN_DIM) / 8;
    for (int i = (blockIdx.x - OUT_DIM) * 256 + tid; i < n8; i += stride) {
      f32x4 a = *(const f32x4*)&X[(size_t)i * 8];
      f32x4 b = *(const f32x4*)&X[(size_t)i * 8 + 4];
      u16x8 r;
      r[0] = f2bf(a[0]); r[1] = f2bf(a[1]); r[2] = f2bf(a[2]); r[3] = f2bf(a[3]);
      r[4] = f2bf(b[0]); r[5] = f2bf(b[1]); r[6] = f2bf(b[2]); r[7] = f2bf(b[3]);
      *(u16x8*)&Xb[(size_t)i * 8] = r;
    }
  }
}

// ---------------------------------------------------------------------------
// GEMM: C[M][N] f32 = A[M][K](bf16) x B[N][K](bf16, B^T layout).
// R15 = R10 K-pipeline VERBATIM (session-best schedule), wrapped in an
// outer loop over TWO bn-tiles per block (grid 256 = one dispatch round):
//   swz=(bid&7)*32+(bid>>3); bm=swz&31; pair=swz>>5; bn=pair*512+tt*256.
// Each XCD's 32 blocks share one bn-pair -> its 4 MB W-pair is L2-resident
// (W fetched from HBM once); A streams via L3; one pipeline prologue saved.
// Seam safety: tile-2 prologue stages regions whose tile-1 readers finished
// >=6 barriers earlier; seam gate VM(8) retires (oldest-first) all 32
// epilogue stores + exactly the (0,0) region.
// Phase (unchanged): [reads][stage][gate][barrier][lgkm0][MFMA]; stages at
// even phases, vmcnt(8) counted gates (never 0 in steady state), tail
// vm8/vm4/vm0. 16x16x32 MFMA, BM=BN=256, BK=64, 8 waves (2Mx4N), ring-2 x
// 64 KiB LDS k-slab regions, involution swizzle o^=((o>>3)&0x30)
// (0 conflicts), setprio, XCD swizzle.
// ---------------------------------------------------------------------------
__global__ __launch_bounds__(512, 1) void gemm_bt_kernel(
    const u16* __restrict__ A,   // [M_DIM][K]
    const u16* __restrict__ B,   // [OUT_DIM][K]
    float*     __restrict__ C) { // [M_DIM][OUT_DIM]
  constexpr int K   = IN_DIM;
  constexpr int NT  = K / 64;    // 64 K-tiles (BK=64)
  constexpr int NIT = NT / 2;    // 32 iterations (2 K-tiles each)
  extern __shared__ char smem[]; // 131072 B

  const int tid  = threadIdx.x;
  const int wave = tid >> 6;
  const int lane = tid & 63;

  // XCD-aware bijective swizzle (grid = 256, %8 == 0); per-XCD fixed bn-pair
  const int swz  = (blockIdx.x & 7) * 32 + (blockIdx.x >> 3);
  const int bm   = (swz & 31) * 256;   // 32 M-blocks
  const int pair = swz >> 5;           // 8 bn-pairs (one per XCD)

  const int wr  = (wave >> 2) * 128;  // 2 M-wave-groups
  const int wc  = (wave & 3) * 64;    // 4 N-wave-groups
  const int fr  = lane & 15;
  const int fkB = (lane >> 4) * 16;   // k-frag byte offset within 64B slab row

  // swizzled read offsets within a 16 KiB region (row stride 64 B)
  int offA[2][4], offB[4];
#pragma unroll
  for (int mq = 0; mq < 2; ++mq)
#pragma unroll
    for (int m = 0; m < 4; ++m) {
      int o = (wr + mq * 64 + m * 16 + fr) * 64 + fkB;
      offA[mq][m] = o ^ ((o >> 3) & 0x30);
    }
#pragma unroll
  for (int n = 0; n < 4; ++n) {
    int o = (wc + n * 16 + fr) * 64 + fkB;
    offB[n] = 16384 + (o ^ ((o >> 3) & 0x30));
  }

  // pre-swizzled global stage sources (inverse involution); A fixed per block
  const int d0 = tid * 16,        d1 = 8192 + tid * 16;
  const int l0 = d0 ^ ((d0 >> 3) & 0x30), l1 = d1 ^ ((d1 >> 3) & 0x30);
  const u16* srcA0 = A + (size_t)(bm + (d0 >> 6)) * K + ((l0 & 63) >> 1);
  const u16* srcA1 = A + (size_t)(bm + (d1 >> 6)) * K + ((l1 & 63) >> 1);
  const int ldsW = wave * 1024;  // wave-uniform dest base (HW adds lane*16)

#define GLD(SRC, DST)                                              \
  __builtin_amdgcn_global_load_lds(                                \
      (const __attribute__((address_space(1))) void*)(SRC),        \
      (__attribute__((address_space(3))) void*)(DST), 16, 0, 0)
#define VM8 asm volatile("s_waitcnt vmcnt(8)" ::: "memory")
#define VM4 asm volatile("s_waitcnt vmcnt(4)" ::: "memory")
#define VM0 asm volatile("s_waitcnt vmcnt(0)" ::: "memory")

  for (int tt = 0; tt < 2; ++tt) {
    const int bn = pair * 512 + tt * 256;
    const u16* srcB0 = B + (size_t)(bn + (d0 >> 6)) * K + ((l0 & 63) >> 1);
    const u16* srcB1 = B + (size_t)(bn + (d1 >> 6)) * K + ((l1 & 63) >> 1);

    // stage one full 32 KiB k-slab region (A-part + B-part = 4 loads)
    auto stageRegion = [&](int bufi, int ks, int tile) {
      char* base = smem + bufi * 65536 + ks * 32768 + ldsW;
      const u16* a0 = srcA0 + tile * 64 + ks * 32;
      const u16* a1 = srcA1 + tile * 64 + ks * 32;
      const u16* b0 = srcB0 + tile * 64 + ks * 32;
      const u16* b1 = srcB1 + tile * 64 + ks * 32;
      GLD(a0, base);
      GLD(a1, base + 8192);
      GLD(b0, base + 16384);
      GLD(b1, base + 24576);
    };

    f32x4 acc[8][4] = {};
    bf16x8 aq[4], bq[4];

    // prologue: (0,0)@0, (0,1)@0, (1,0)@1 = 12 loads; VM8 retires (0,0)
    // (at tt=1 it also retires, oldest-first, the 32 epilogue stores).
    stageRegion(0, 0, 0);
    stageRegion(0, 1, 0);
    stageRegion(1, 0, 1);
    VM8;
    __builtin_amdgcn_s_barrier();

    // single-barrier phase: reads; stage; gate; barrier; lgkm0; MFMA.
#define PHASE(BUFI, KS, MQ, READB, STAGE, GATE)                              \
  {                                                                          \
    const char* rb = smem + (BUFI) * 65536 + (KS) * 32768;                   \
    if (READB) {                                                             \
      _Pragma("unroll")                                                      \
      for (int n = 0; n < 4; ++n) bq[n] = *(const bf16x8*)(rb + offB[n]);    \
    }                                                                        \
    _Pragma("unroll")                                                        \
    for (int m = 0; m < 4; ++m) aq[m] = *(const bf16x8*)(rb + offA[MQ][m]);  \
    STAGE;                                                                   \
    GATE;                                                                    \
    __builtin_amdgcn_s_barrier();                                            \
    asm volatile("s_waitcnt lgkmcnt(0)" ::: "memory");                       \
    __builtin_amdgcn_s_setprio(1);                                           \
    _Pragma("unroll")                                                        \
    for (int m = 0; m < 4; ++m)                                              \
      _Pragma("unroll")                                                      \
      for (int n = 0; n < 4; ++n)                                            \
        acc[(MQ) * 4 + m][n] = __builtin_amdgcn_mfma_f32_16x16x32_bf16(      \
            aq[m], bq[n], acc[(MQ) * 4 + m][n], 0, 0, 0);                    \
    __builtin_amdgcn_s_setprio(0);                                           \
  }

    for (int i = 0; i < NIT - 1; ++i) {
      const int t0 = 2 * i;
      PHASE(0, 0, 0, 1, , )
      PHASE(0, 0, 1, 0, stageRegion(1, 1, t0 + 1), VM8)
      PHASE(0, 1, 0, 1, , )
      PHASE(0, 1, 1, 0, stageRegion(0, 0, t0 + 2), VM8)
      PHASE(1, 0, 0, 1, , )
      PHASE(1, 0, 1, 0, stageRegion(0, 1, t0 + 2), VM8)
      PHASE(1, 1, 0, 1, , )
      PHASE(1, 1, 1, 0, stageRegion(1, 0, t0 + 3), VM8)
    }

    // peeled last iteration (t0 = NT-2): gates taper vm8 / vm4 / vm0 / none.
    PHASE(0, 0, 0, 1, , )
    PHASE(0, 0, 1, 0, stageRegion(1, 1, NT - 1), VM8)
    PHASE(0, 1, 0, 1, , )
    PHASE(0, 1, 1, 0, , VM4)
    PHASE(1, 0, 0, 1, , )
    PHASE(1, 0, 1, 0, , VM0)
    PHASE(1, 1, 0, 1, , )
    PHASE(1, 1, 1, 0, , )
#undef PHASE

    // epilogue: C/D layout col=lane&15, row=(lane>>4)*4+j (m89-verified)
#pragma unroll
    for (int h = 0; h < 8; ++h)
#pragma unroll
      for (int n = 0; n < 4; ++n) {
        const int col = bn + wc + n * 16 + fr;
#pragma unroll
        for (int j = 0; j < 4; ++j) {
          const int row = bm + wr + h * 16 + (lane >> 4) * 4 + j;
          C[(size_t)row * OUT_DIM + col] = acc[h][n][j];
        }
      }
  }
#undef GLD
#undef VM8
#undef VM4
#undef VM0
}

// ---------------------------------------------------------------------------
extern "C" void kernel_launch(void* const* d_in, const int* in_sizes, int n_in,
                              void* d_out, int out_size, void* d_ws, size_t ws_size,
                              hipStream_t stream) {
  const float* x        = (const float*)d_in[0];
  const float* codebook = (const float*)d_in[1];
  const float* scales   = (const float*)d_in[2];
  const int*   indices  = (const int*)d_in[3];
  const int*   signs    = (const int*)d_in[4];
  float* out = (float*)d_out;

  u16* W  = (u16*)d_ws;
  u16* Xb = (u16*)d_ws + (size_t)OUT_DIM * IN_DIM;

  (void)hipFuncSetAttribute((const void*)gemm_bt_kernel,
                            hipFuncAttributeMaxDynamicSharedMemorySize, 131072);

  prep_kernel<<<OUT_DIM + 2048, 256, 0, stream>>>(codebook, scales, indices,
                                                  signs, x, W, Xb);
  gemm_bt_kernel<<<(M_DIM / 256) * (OUT_DIM / 512), 512, 131072, stream>>>(Xb, W, out);
}

// Round 16
// 274.556 us; speedup vs baseline: 1.1454x; 1.1454x over previous
//
#include <hip/hip_runtime.h>
#include <hip/hip_bf16.h>

typedef unsigned short u16;
typedef unsigned int u32;
typedef float f32x4 __attribute__((ext_vector_type(4)));
typedef u16 u16x4 __attribute__((ext_vector_type(4)));
typedef u16 u16x8 __attribute__((ext_vector_type(8)));
typedef __bf16 bf16x8 __attribute__((ext_vector_type(8)));

#define OUT_DIM 4096
#define IN_DIM  4096
#define M_DIM   8192   // 4 * 2048

__device__ __forceinline__ u16 f2bf(float f) {
  u32 u = __builtin_bit_cast(u32, f);
  return (u16)((u + 0x7FFFu + ((u >> 16) & 1u)) >> 16);
}

// ---------------------------------------------------------------------------
// Combined prep kernel (single dispatch, saves a launch gap):
//  blocks [0, 4096): build W row o = blockIdx.x
//    codebook gather + sign unpack + 2-level inverse Haar + scale -> bf16
//  blocks [4096, 6144): X f32 -> bf16 conversion (grid-stride)
// ---------------------------------------------------------------------------
__global__ __launch_bounds__(256) void prep_kernel(
    const float* __restrict__ codebook, const float* __restrict__ scales,
    const int* __restrict__ indices, const int* __restrict__ signs,
    const float* __restrict__ X,
    u16* __restrict__ W, u16* __restrict__ Xb) {
  __shared__ float c[IN_DIM];
  const int tid = threadIdx.x;

  if (blockIdx.x < OUT_DIM) {
    const int o = blockIdx.x;
    for (int g = tid; g < IN_DIM / 8; g += 256) {
      const int idx = indices[o * (IN_DIM / 8) + g];
      const int sp  = signs[o * (IN_DIM / 8) + g];
      f32x4 c0 = *(const f32x4*)&codebook[idx * 8];
      f32x4 c1 = *(const f32x4*)&codebook[idx * 8 + 4];
      float v[8] = {c0[0], c0[1], c0[2], c0[3], c1[0], c1[1], c1[2], c1[3]};
#pragma unroll
      for (int j = 0; j < 8; ++j)
        c[g * 8 + j] = ((sp >> j) & 1) ? v[j] : -v[j];
    }
    __syncthreads();
    const float scale = scales[o];
    const float S = 0.70710678118654752440f;
    for (int t = tid; t < IN_DIM / 4; t += 256) {
      float a   = c[t];
      float d1  = c[IN_DIM / 4 + t];
      float d2a = c[IN_DIM / 2 + 2 * t];
      float d2b = c[IN_DIM / 2 + 2 * t + 1];
      float e  = (a + d1) * S;
      float od = (a - d1) * S;
      u16x4 w;
      w[0] = f2bf((e  + d2a) * S * scale);
      w[1] = f2bf((e  - d2a) * S * scale);
      w[2] = f2bf((od + d2b) * S * scale);
      w[3] = f2bf((od - d2b) * S * scale);
      *(u16x4*)&W[(size_t)o * IN_DIM + 4 * t] = w;
    }
  } else {
    const int stride = 2048 * 256;
    const int n8 = (M_DIM * IN_DIM) / 8;
    for (int i = (blockIdx.x - OUT_DIM) * 256 + tid; i < n8; i += stride) {
      f32x4 a = *(const f32x4*)&X[(size_t)i * 8];
      f32x4 b = *(const f32x4*)&X[(size_t)i * 8 + 4];
      u16x8 r;
      r[0] = f2bf(a[0]); r[1] = f2bf(a[1]); r[2] = f2bf(a[2]); r[3] = f2bf(a[3]);
      r[4] = f2bf(b[0]); r[5] = f2bf(b[1]); r[6] = f2bf(b[2]); r[7] = f2bf(b[3]);
      *(u16x8*)&Xb[(size_t)i * 8] = r;
    }
  }
}

// ---------------------------------------------------------------------------
// GEMM: C[M][N] f32 = A[M][K](bf16) x B[N][K](bf16, B^T layout).
// Session-best schedule (R10/R14): SINGLE barrier per phase:
//   [reads][stage][gate][barrier][lgkm0][MFMA]
// so ds_reads of phase p+1 overlap the MFMA cluster of phase p.
// Safety: all reads of phase r complete before barrier(r+1) (each wave's
// lgkm-wait(r) precedes its reads(r+1) which precede barrier(r+1)); every
// stage targets a region last read 2 phases earlier. Stages at even phases:
// p2:(1,1)@t+1  p4:(0,0)@t+2  p6:(0,1)@t+2  p8:(1,0)@t+3; gates vmcnt(8)
// at every even phase (retires a region staged 4 phases ~4400cy earlier);
// tail tapers vm8/vm4/vm0. Max 12 loads in flight, never vmcnt(0) in
// steady state. 16x16x32 MFMA, BM=BN=256, BK=64, 8 waves (2Mx4N), ring-2 x
// 64 KiB LDS k-slab regions, involution swizzle o^=((o>>3)&0x30)
// (0 conflicts), setprio, XCD swizzle (grid 512, A-panel shared in-XCD).
// ---------------------------------------------------------------------------
__global__ __launch_bounds__(512, 1) void gemm_bt_kernel(
    const u16* __restrict__ A,   // [M_DIM][K]
    const u16* __restrict__ B,   // [OUT_DIM][K]
    float*     __restrict__ C) { // [M_DIM][OUT_DIM]
  constexpr int K   = IN_DIM;
  constexpr int NT  = K / 64;    // 64 K-tiles (BK=64)
  constexpr int NIT = NT / 2;    // 32 iterations (2 K-tiles each)
  extern __shared__ char smem[]; // 131072 B

  const int tid  = threadIdx.x;
  const int wave = tid >> 6;
  const int lane = tid & 63;

  // XCD-aware bijective swizzle (grid = 512, %8 == 0)
  const int swz = (blockIdx.x & 7) * 64 + (blockIdx.x >> 3);
  const int bm = (swz >> 4) * 256;   // 32 M-blocks
  const int bn = (swz & 15) * 256;   // 16 N-blocks

  const int wr  = (wave >> 2) * 128;  // 2 M-wave-groups
  const int wc  = (wave & 3) * 64;    // 4 N-wave-groups
  const int fr  = lane & 15;
  const int fkB = (lane >> 4) * 16;   // k-frag byte offset within 64B slab row

  // swizzled read offsets within a 16 KiB region (row stride 64 B)
  int offA[2][4], offB[4];
#pragma unroll
  for (int mq = 0; mq < 2; ++mq)
#pragma unroll
    for (int m = 0; m < 4; ++m) {
      int o = (wr + mq * 64 + m * 16 + fr) * 64 + fkB;
      offA[mq][m] = o ^ ((o >> 3) & 0x30);
    }
#pragma unroll
  for (int n = 0; n < 4; ++n) {
    int o = (wc + n * 16 + fr) * 64 + fkB;
    offB[n] = 16384 + (o ^ ((o >> 3) & 0x30));
  }

  // pre-swizzled global stage sources (inverse involution)
  const int d0 = tid * 16,        d1 = 8192 + tid * 16;
  const int l0 = d0 ^ ((d0 >> 3) & 0x30), l1 = d1 ^ ((d1 >> 3) & 0x30);
  const u16* srcA0 = A + (size_t)(bm + (d0 >> 6)) * K + ((l0 & 63) >> 1);
  const u16* srcA1 = A + (size_t)(bm + (d1 >> 6)) * K + ((l1 & 63) >> 1);
  const u16* srcB0 = B + (size_t)(bn + (d0 >> 6)) * K + ((l0 & 63) >> 1);
  const u16* srcB1 = B + (size_t)(bn + (d1 >> 6)) * K + ((l1 & 63) >> 1);
  const int ldsW = wave * 1024;  // wave-uniform dest base (HW adds lane*16)

#define GLD(SRC, DST)                                              \
  __builtin_amdgcn_global_load_lds(                                \
      (const __attribute__((address_space(1))) void*)(SRC),        \
      (__attribute__((address_space(3))) void*)(DST), 16, 0, 0)

  // stage one full 32 KiB k-slab region (A-part + B-part = 4 loads)
  auto stageRegion = [&](int bufi, int ks, int tile) {
    char* base = smem + bufi * 65536 + ks * 32768 + ldsW;
    const u16* a0 = srcA0 + tile * 64 + ks * 32;
    const u16* a1 = srcA1 + tile * 64 + ks * 32;
    const u16* b0 = srcB0 + tile * 64 + ks * 32;
    const u16* b1 = srcB1 + tile * 64 + ks * 32;
    GLD(a0, base);
    GLD(a1, base + 8192);
    GLD(b0, base + 16384);
    GLD(b1, base + 24576);
  };

  f32x4 acc[8][4] = {};
  bf16x8 aq[4], bq[4];

  // prologue: (0,0)@0, (0,1)@0, (1,0)@1 = 12 loads; retire (0,0) only.
  stageRegion(0, 0, 0);
  stageRegion(0, 1, 0);
  stageRegion(1, 0, 1);
  asm volatile("s_waitcnt vmcnt(8)" ::: "memory");
  __builtin_amdgcn_s_barrier();

  // single-barrier phase: reads; stage; gate; barrier; lgkm0; MFMA.
#define PHASE(BUFI, KS, MQ, READB, STAGE, GATE)                              \
  {                                                                          \
    const char* rb = smem + (BUFI) * 65536 + (KS) * 32768;                   \
    if (READB) {                                                             \
      _Pragma("unroll")                                                      \
      for (int n = 0; n < 4; ++n) bq[n] = *(const bf16x8*)(rb + offB[n]);    \
    }                                                                        \
    _Pragma("unroll")                                                        \
    for (int m = 0; m < 4; ++m) aq[m] = *(const bf16x8*)(rb + offA[MQ][m]);  \
    STAGE;                                                                   \
    GATE;                                                                    \
    __builtin_amdgcn_s_barrier();                                            \
    asm volatile("s_waitcnt lgkmcnt(0)" ::: "memory");                       \
    __builtin_amdgcn_s_setprio(1);                                           \
    _Pragma("unroll")                                                        \
    for (int m = 0; m < 4; ++m)                                              \
      _Pragma("unroll")                                                      \
      for (int n = 0; n < 4; ++n)                                            \
        acc[(MQ) * 4 + m][n] = __builtin_amdgcn_mfma_f32_16x16x32_bf16(      \
            aq[m], bq[n], acc[(MQ) * 4 + m][n], 0, 0, 0);                    \
    __builtin_amdgcn_s_setprio(0);                                           \
  }

#define VM8 asm volatile("s_waitcnt vmcnt(8)" ::: "memory")
#define VM4 asm volatile("s_waitcnt vmcnt(4)" ::: "memory")
#define VM0 asm volatile("s_waitcnt vmcnt(0)" ::: "memory")

  for (int i = 0; i < NIT - 1; ++i) {
    const int t0 = 2 * i;
    PHASE(0, 0, 0, 1, , )
    PHASE(0, 0, 1, 0, stageRegion(1, 1, t0 + 1), VM8)
    PHASE(0, 1, 0, 1, , )
    PHASE(0, 1, 1, 0, stageRegion(0, 0, t0 + 2), VM8)
    PHASE(1, 0, 0, 1, , )
    PHASE(1, 0, 1, 0, stageRegion(0, 1, t0 + 2), VM8)
    PHASE(1, 1, 0, 1, , )
    PHASE(1, 1, 1, 0, stageRegion(1, 0, t0 + 3), VM8)
  }

  // peeled last iteration (t0 = NT-2): only (1,1)@NT-1 still staged;
  // gates taper vm8 / vm4 / vm0 / none.
  PHASE(0, 0, 0, 1, , )
  PHASE(0, 0, 1, 0, stageRegion(1, 1, NT - 1), VM8)
  PHASE(0, 1, 0, 1, , )
  PHASE(0, 1, 1, 0, , VM4)
  PHASE(1, 0, 0, 1, , )
  PHASE(1, 0, 1, 0, , VM0)
  PHASE(1, 1, 0, 1, , )
  PHASE(1, 1, 1, 0, , )
#undef PHASE
#undef GLD
#undef VM8
#undef VM4
#undef VM0

  // epilogue: C/D layout col=lane&15, row=(lane>>4)*4+j (m89-verified)
#pragma unroll
  for (int h = 0; h < 8; ++h)
#pragma unroll
    for (int n = 0; n < 4; ++n) {
      const int col = bn + wc + n * 16 + fr;
#pragma unroll
      for (int j = 0; j < 4; ++j) {
        const int row = bm + wr + h * 16 + (lane >> 4) * 4 + j;
        C[(size_t)row * OUT_DIM + col] = acc[h][n][j];
      }
    }
}

// ---------------------------------------------------------------------------
extern "C" void kernel_launch(void* const* d_in, const int* in_sizes, int n_in,
                              void* d_out, int out_size, void* d_ws, size_t ws_size,
                              hipStream_t stream) {
  const float* x        = (const float*)d_in[0];
  const float* codebook = (const float*)d_in[1];
  const float* scales   = (const float*)d_in[2];
  const int*   indices  = (const int*)d_in[3];
  const int*   signs    = (const int*)d_in[4];
  float* out = (float*)d_out;

  u16* W  = (u16*)d_ws;
  u16* Xb = (u16*)d_ws + (size_t)OUT_DIM * IN_DIM;

  (void)hipFuncSetAttribute((const void*)gemm_bt_kernel,
                            hipFuncAttributeMaxDynamicSharedMemorySize, 131072);

  prep_kernel<<<OUT_DIM + 2048, 256, 0, stream>>>(codebook, scales, indices,
                                                  signs, x, W, Xb);
  gemm_bt_kernel<<<(M_DIM / 256) * (OUT_DIM / 256), 512, 131072, stream>>>(Xb, W, out);
}